// Round 9
// baseline (51.206 us; speedup 1.0000x reference)
//
#include <hip/hip_runtime.h>
#include <hip/hip_bf16.h>

#define NN 96
#define DD 64
#define HH 256
#define H2 128

typedef float v2f __attribute__((ext_vector_type(2)));

// ---------------- Kernel A: projections ----------------
// tc written h-paired: tcP[(hp*NN + k)*2 + (h&1)] so conf loads float2
// h-pairs for packed math.
__global__ __launch_bounds__(256) void proj_kernel(
    const float* __restrict__ X, const float* __restrict__ W1, const float* __restrict__ b1,
    const float* __restrict__ V1, const float* __restrict__ c1,
    float* __restrict__ pi, float* __restrict__ pj,
    float* __restrict__ ta, float* __restrict__ tb, float* __restrict__ tcP)
{
    const int i = blockIdx.x;
    const int h = threadIdx.x;          // 0..255
    __shared__ float xs[DD];
    if (h < DD) xs[h] = X[i*DD + h];
    __syncthreads();
    float aPi = 0.f, aPj = 0.f, aTa = 0.f, aTb = 0.f, aTc = 0.f;
    #pragma unroll 8
    for (int d = 0; d < DD; ++d) {
        const float x = xs[d];
        aPi = fmaf(x, W1[d*HH + h],          aPi);
        aPj = fmaf(x, W1[(DD + d)*HH + h],   aPj);
        aTa = fmaf(x, V1[d*HH + h],          aTa);
        aTb = fmaf(x, V1[(DD + d)*HH + h],   aTb);
        aTc = fmaf(x, V1[(2*DD + d)*HH + h], aTc);
    }
    pi[i*HH + h] = aPi + b1[h];
    pj[i*HH + h] = aPj;
    ta[i*HH + h] = aTa + c1[h];
    tb[i*HH + h] = aTb;
    tcP[((h >> 1)*NN + i)*2 + (h & 1)] = aTc;
}

// ---------------- Fused kernel: causal (by<8) + conf (by>=8) ----------------
// LDS shrunk to 12.4 KB (part halved via two-phase quarter-accumulate; conf
// 6-j blocks) -> 8 blocks/CU (thread-capped, launch_bounds(256,8)), 32
// waves/CU. conf remapped to m=1 x k=3: 1 DS-b128 per 24 packed-VALU inst
// (3x less DS). causal inner q-loop and packed math unchanged (proven).
__global__ __launch_bounds__(256, 8) void fused_kernel(
    const float* __restrict__ pi, const float* __restrict__ pj,
    const float* __restrict__ W2, const float* __restrict__ b2,
    const float* __restrict__ W3, const float* __restrict__ b3,
    const float* __restrict__ ta, const float* __restrict__ tb,
    const float* __restrict__ tcP, const float* __restrict__ V2,
    const float* __restrict__ c2, float* __restrict__ out)
{
    __shared__ float smem[3072 + 24];   // causal: hb[256][12] alias part[2][64][2][12], +red
    const int i  = blockIdx.x;
    const int by = blockIdx.y;
    const int t  = threadIdx.x;         // 0..255

    if (by < 8) {
        // ================= causal path =================
        const int j0 = by * 12;
        const int c2c = t & 63;
        const int qt  = t >> 6;         // 0..3

        float (*hb)[12]          = (float(*)[12])smem;          // [256][12]
        float (*part)[64][2][12] = (float(*)[64][2][12])smem;   // [2][64][2][12]
        float (*red)[12]         = (float(*)[12])(smem + 3072); // [2][12]

        // ---- stage hbT[h][jj] = relu(pi[i][h] + pj[j][h]), h = t ----
        {
            const float p_i = pi[i*HH + t];
            #pragma unroll
            for (int jj = 0; jj < 12; ++jj)
                hb[t][jj] = fmaxf(p_i + pj[(j0 + jj)*HH + t], 0.f);
        }
        __syncthreads();

        v2f acc0[6], acc1[6];
        #pragma unroll
        for (int p = 0; p < 6; ++p) { acc0[p] = (v2f)(0.f); acc1[p] = (v2f)(0.f); }

        const float* __restrict__ w2p = W2 + (qt*64)*H2 + c2c;
        #pragma unroll 2
        for (int q = 0; q < 64; ++q) {
            const float wa = w2p[q*H2];
            const float wb = w2p[q*H2 + 64];
            const v2f wa2 = {wa, wa};
            const v2f wb2 = {wb, wb};
            const int hq = qt*64 + q;
            const float4 hA = *(const float4*)&hb[hq][0];
            const float4 hB = *(const float4*)&hb[hq][4];
            const float4 hC = *(const float4*)&hb[hq][8];
            const v2f hp[6] = {{hA.x,hA.y},{hA.z,hA.w},
                               {hB.x,hB.y},{hB.z,hB.w},
                               {hC.x,hC.y},{hC.z,hC.w}};
            #pragma unroll
            for (int p = 0; p < 6; ++p) {
                acc0[p] += hp[p] * wa2;     // v_pk_fma_f32
                acc1[p] += hp[p] * wb2;
            }
        }
        __syncthreads();          // all hb reads done before overwrite

        // ---- two-phase partials: qt 0,1 write; qt 2,3 accumulate ----
        if (qt < 2) {
            #pragma unroll
            for (int b = 0; b < 3; ++b) {
                float4 p0, p1;
                p0.x = acc0[b*2].x; p0.y = acc0[b*2].y; p0.z = acc0[b*2+1].x; p0.w = acc0[b*2+1].y;
                p1.x = acc1[b*2].x; p1.y = acc1[b*2].y; p1.z = acc1[b*2+1].x; p1.w = acc1[b*2+1].y;
                *(float4*)&part[qt][c2c][0][b*4] = p0;
                *(float4*)&part[qt][c2c][1][b*4] = p1;
            }
        }
        __syncthreads();
        if (qt >= 2) {
            #pragma unroll
            for (int b = 0; b < 3; ++b) {
                float4 p0 = *(const float4*)&part[qt-2][c2c][0][b*4];
                float4 p1 = *(const float4*)&part[qt-2][c2c][1][b*4];
                p0.x += acc0[b*2].x; p0.y += acc0[b*2].y; p0.z += acc0[b*2+1].x; p0.w += acc0[b*2+1].y;
                p1.x += acc1[b*2].x; p1.y += acc1[b*2].y; p1.z += acc1[b*2+1].x; p1.w += acc1[b*2+1].y;
                *(float4*)&part[qt-2][c2c][0][b*4] = p0;
                *(float4*)&part[qt-2][c2c][1][b*4] = p1;
            }
        }
        __syncthreads();

        // ---- reduce halves, layer2 bias+relu, layer3 dot over 128 c ----
        if (t < 128) {
            const int cl = t & 63;
            const int cc = t >> 6;
            const float b2c = b2[t];
            const float w3c = W3[t];
            float v[12];
            #pragma unroll
            for (int b = 0; b < 3; ++b) {
                const float4 pa = *(const float4*)&part[0][cl][cc][b*4];
                const float4 pb = *(const float4*)&part[1][cl][cc][b*4];
                v[b*4+0] = fmaxf(pa.x + pb.x + b2c, 0.f) * w3c;
                v[b*4+1] = fmaxf(pa.y + pb.y + b2c, 0.f) * w3c;
                v[b*4+2] = fmaxf(pa.z + pb.z + b2c, 0.f) * w3c;
                v[b*4+3] = fmaxf(pa.w + pb.w + b2c, 0.f) * w3c;
            }
            #pragma unroll
            for (int jj = 0; jj < 12; ++jj) {
                float s = v[jj];
                #pragma unroll
                for (int off = 32; off; off >>= 1) s += __shfl_down(s, off, 64);
                if ((t & 63) == 0) red[t >> 6][jj] = s;
            }
        }
        __syncthreads();
        if (t < 12) {
            const int j = j0 + t;
            const float s = red[0][t] + red[1][t] + b3[0];
            out[i*NN + j] = (i == j) ? 0.f : 1.f / (1.f + __expf(-s));
        }
    } else {
        // ================= conf path: 6 j, m=1 x k=3 =================
        const int j0 = (by - 8) * 6;
        float (*sbuf)[HH] = (float(*)[HH])smem;     // [6][256]
        float* outc = out + NN*NN;

        // ---- stage s[jj][h] = ta[i][h] + tb[j][h] (all 256 threads) ----
        for (int idx = t; idx < 6*HH/4; idx += 256) {
            const int jj = idx >> 6;            // 64 float4s per row
            const int h4 = (idx & 63) << 2;
            const float4 a = *(const float4*)&ta[i*HH + h4];
            const float4 b = *(const float4*)&tb[(j0 + jj)*HH + h4];
            float4 s; s.x = a.x + b.x; s.y = a.y + b.y; s.z = a.z + b.z; s.w = a.w + b.w;
            *(float4*)&sbuf[jj][h4] = s;
        }
        __syncthreads();

        if (t < 192) {
            const int jg = t >> 5;              // 0..5 (one j per thread)
            const int l  = t & 31;              // k-triple lane
            const int k0 = 3*l;                 // k = k0..k0+2

            v2f acc[3];                         // [kk], packed over h-pair
            acc[0] = (v2f)(0.f); acc[1] = (v2f)(0.f); acc[2] = (v2f)(0.f);

            const float* __restrict__ sb = &sbuf[jg][0];

            #pragma unroll 2
            for (int h0 = 0; h0 < HH; h0 += 4) {
                const int hp = h0 >> 1;
                const float2 tA0 = *(const float2*)&tcP[(hp*NN + k0 + 0)*2];
                const float2 tA1 = *(const float2*)&tcP[(hp*NN + k0 + 1)*2];
                const float2 tA2 = *(const float2*)&tcP[(hp*NN + k0 + 2)*2];
                const float2 tB0 = *(const float2*)&tcP[((hp+1)*NN + k0 + 0)*2];
                const float2 tB1 = *(const float2*)&tcP[((hp+1)*NN + k0 + 1)*2];
                const float2 tB2 = *(const float2*)&tcP[((hp+1)*NN + k0 + 2)*2];
                const float4 vv = *(const float4*)&V2[h0];        // uniform
                const float4 sA = *(const float4*)&sb[h0];
                const v2f sp0 = {sA.x, sA.y}, sp1 = {sA.z, sA.w};
                const v2f va01 = {vv.x, vv.y}, va23 = {vv.z, vv.w};
                v2f x;
                x = sp0 + (v2f){tA0.x, tA0.y};
                x.x = fmaxf(x.x, 0.f); x.y = fmaxf(x.y, 0.f);
                acc[0] += x * va01;
                x = sp1 + (v2f){tB0.x, tB0.y};
                x.x = fmaxf(x.x, 0.f); x.y = fmaxf(x.y, 0.f);
                acc[0] += x * va23;
                x = sp0 + (v2f){tA1.x, tA1.y};
                x.x = fmaxf(x.x, 0.f); x.y = fmaxf(x.y, 0.f);
                acc[1] += x * va01;
                x = sp1 + (v2f){tB1.x, tB1.y};
                x.x = fmaxf(x.x, 0.f); x.y = fmaxf(x.y, 0.f);
                acc[1] += x * va23;
                x = sp0 + (v2f){tA2.x, tA2.y};
                x.x = fmaxf(x.x, 0.f); x.y = fmaxf(x.y, 0.f);
                acc[2] += x * va01;
                x = sp1 + (v2f){tB2.x, tB2.y};
                x.x = fmaxf(x.x, 0.f); x.y = fmaxf(x.y, 0.f);
                acc[2] += x * va23;
            }

            const float c2v = c2[0];
            const int j = j0 + jg;
            #pragma unroll
            for (int kk = 0; kk < 3; ++kk) {
                const int k = k0 + kk;
                const float a = acc[kk].x + acc[kk].y;
                float val = 1.f / (1.f + __expf(-(a + c2v)));
                if (i == j || i == k || j == k) val = 0.f;
                outc[(i*NN + j)*NN + k] = val;
            }
        }
    }
}

extern "C" void kernel_launch(void* const* d_in, const int* in_sizes, int n_in,
                              void* d_out, int out_size, void* d_ws, size_t ws_size,
                              hipStream_t stream) {
    const float* X  = (const float*)d_in[0];
    // d_in[1] = edge_index (unused by reference)
    const float* W1 = (const float*)d_in[2];
    const float* b1 = (const float*)d_in[3];
    const float* W2 = (const float*)d_in[4];
    const float* b2 = (const float*)d_in[5];
    const float* W3 = (const float*)d_in[6];
    const float* b3 = (const float*)d_in[7];
    const float* V1 = (const float*)d_in[8];
    const float* c1 = (const float*)d_in[9];
    const float* V2 = (const float*)d_in[10];
    const float* c2 = (const float*)d_in[11];

    float* out = (float*)d_out;
    float* ws  = (float*)d_ws;
    float* pi  = ws;                 // 96*256
    float* pj  = pi + NN*HH;
    float* ta  = pj + NN*HH;
    float* tb  = ta + NN*HH;
    float* tcP = tb + NN*HH;         // 128*96 float2 = 256*96 floats

    proj_kernel<<<NN, 256, 0, stream>>>(X, W1, b1, V1, c1, pi, pj, ta, tb, tcP);
    fused_kernel<<<dim3(NN, 24), 256, 0, stream>>>(pi, pj, W2, b2, W3, b3,
                                                   ta, tb, tcP, V2, c2, out);
}

// Round 10
// 45.231 us; speedup vs baseline: 1.1321x; 1.1321x over previous
//
#include <hip/hip_runtime.h>
#include <hip/hip_bf16.h>

#define NN 96
#define DD 64
#define HH 256
#define H2 128

typedef float v2f __attribute__((ext_vector_type(2)));

// ---------------- Kernel A: projections ----------------
// tc written h-paired: tcP[(hp*NN + k)*2 + (h&1)] so conf loads float2
// h-pairs (float4 = k-pair of h-pairs) for packed math.
__global__ __launch_bounds__(256) void proj_kernel(
    const float* __restrict__ X, const float* __restrict__ W1, const float* __restrict__ b1,
    const float* __restrict__ V1, const float* __restrict__ c1,
    float* __restrict__ pi, float* __restrict__ pj,
    float* __restrict__ ta, float* __restrict__ tb, float* __restrict__ tcP)
{
    const int i = blockIdx.x;
    const int h = threadIdx.x;          // 0..255
    __shared__ float xs[DD];
    if (h < DD) xs[h] = X[i*DD + h];
    __syncthreads();
    float aPi = 0.f, aPj = 0.f, aTa = 0.f, aTb = 0.f, aTc = 0.f;
    #pragma unroll 8
    for (int d = 0; d < DD; ++d) {
        const float x = xs[d];
        aPi = fmaf(x, W1[d*HH + h],          aPi);
        aPj = fmaf(x, W1[(DD + d)*HH + h],   aPj);
        aTa = fmaf(x, V1[d*HH + h],          aTa);
        aTb = fmaf(x, V1[(DD + d)*HH + h],   aTb);
        aTc = fmaf(x, V1[(2*DD + d)*HH + h], aTc);
    }
    pi[i*HH + h] = aPi + b1[h];
    pj[i*HH + h] = aPj;
    ta[i*HH + h] = aTa + c1[h];
    tb[i*HH + h] = aTb;
    tcP[((h >> 1)*NN + i)*2 + (h & 1)] = aTc;
}

// ---------------- Fused kernel: causal (by<8) + conf (by>=8) ----------------
// R7-proven structure (packed f32, grid (96,16), 6 blocks/CU). This round:
// conf path de-convoyed — each of its 3 waves starts the h-chunk loop at a
// rotated offset (21*w chunks) so concurrent waves touch disjoint tcP lines
// (tcP = 96 KB > L1), and unroll deepened to 8 for more load lookahead.
// causal + proj byte-identical to R7.
__global__ __launch_bounds__(256) void fused_kernel(
    const float* __restrict__ pi, const float* __restrict__ pj,
    const float* __restrict__ W2, const float* __restrict__ b2,
    const float* __restrict__ W3, const float* __restrict__ b3,
    const float* __restrict__ ta, const float* __restrict__ tb,
    const float* __restrict__ tcP, const float* __restrict__ V2,
    const float* __restrict__ c2, float* __restrict__ out)
{
    __shared__ float smem[4*64*2*12 + 2*12];   // causal(6144+24) / conf(3072)
    const int i  = blockIdx.x;
    const int by = blockIdx.y;
    const int t  = threadIdx.x;         // 0..255

    if (by < 8) {
        // ================= causal path (R7-exact) =================
        const int j0 = by * 12;
        const int c2c = t & 63;
        const int qt  = t >> 6;         // 0..3

        float (*hb)[12]          = (float(*)[12])smem;          // [256][12]
        float (*part)[64][2][12] = (float(*)[64][2][12])smem;   // [4][64][2][12]
        float (*red)[12]         = (float(*)[12])(smem + 6144); // [2][12]

        {
            const float p_i = pi[i*HH + t];
            #pragma unroll
            for (int jj = 0; jj < 12; ++jj)
                hb[t][jj] = fmaxf(p_i + pj[(j0 + jj)*HH + t], 0.f);
        }
        __syncthreads();

        v2f acc0[6], acc1[6];
        #pragma unroll
        for (int p = 0; p < 6; ++p) { acc0[p] = (v2f)(0.f); acc1[p] = (v2f)(0.f); }

        const float* __restrict__ w2p = W2 + (qt*64)*H2 + c2c;
        #pragma unroll 2
        for (int q = 0; q < 64; ++q) {
            const float wa = w2p[q*H2];
            const float wb = w2p[q*H2 + 64];
            const v2f wa2 = {wa, wa};
            const v2f wb2 = {wb, wb};
            const int hq = qt*64 + q;
            const float4 hA = *(const float4*)&hb[hq][0];
            const float4 hB = *(const float4*)&hb[hq][4];
            const float4 hC = *(const float4*)&hb[hq][8];
            const v2f hp[6] = {{hA.x,hA.y},{hA.z,hA.w},
                               {hB.x,hB.y},{hB.z,hB.w},
                               {hC.x,hC.y},{hC.z,hC.w}};
            #pragma unroll
            for (int p = 0; p < 6; ++p) {
                acc0[p] += hp[p] * wa2;     // v_pk_fma_f32
                acc1[p] += hp[p] * wb2;
            }
        }
        __syncthreads();

        #pragma unroll
        for (int b = 0; b < 3; ++b) {
            float4 p0, p1;
            p0.x = acc0[b*2].x; p0.y = acc0[b*2].y; p0.z = acc0[b*2+1].x; p0.w = acc0[b*2+1].y;
            p1.x = acc1[b*2].x; p1.y = acc1[b*2].y; p1.z = acc1[b*2+1].x; p1.w = acc1[b*2+1].y;
            *(float4*)&part[qt][c2c][0][b*4] = p0;
            *(float4*)&part[qt][c2c][1][b*4] = p1;
        }
        __syncthreads();

        if (t < 128) {
            const int cl = t & 63;
            const int cc = t >> 6;
            const float b2c = b2[t];
            const float w3c = W3[t];
            float v[12];
            #pragma unroll
            for (int b = 0; b < 3; ++b) {
                float4 s; s.x = 0.f; s.y = 0.f; s.z = 0.f; s.w = 0.f;
                #pragma unroll
                for (int qq = 0; qq < 4; ++qq) {
                    const float4 p = *(const float4*)&part[qq][cl][cc][b*4];
                    s.x += p.x; s.y += p.y; s.z += p.z; s.w += p.w;
                }
                v[b*4+0] = fmaxf(s.x + b2c, 0.f) * w3c;
                v[b*4+1] = fmaxf(s.y + b2c, 0.f) * w3c;
                v[b*4+2] = fmaxf(s.z + b2c, 0.f) * w3c;
                v[b*4+3] = fmaxf(s.w + b2c, 0.f) * w3c;
            }
            #pragma unroll
            for (int jj = 0; jj < 12; ++jj) {
                float s = v[jj];
                #pragma unroll
                for (int off = 32; off; off >>= 1) s += __shfl_down(s, off, 64);
                if ((t & 63) == 0) red[t >> 6][jj] = s;
            }
        }
        __syncthreads();
        if (t < 12) {
            const int j = j0 + t;
            const float s = red[0][t] + red[1][t] + b3[0];
            out[i*NN + j] = (i == j) ? 0.f : 1.f / (1.f + __expf(-s));
        }
    } else {
        // ================= conf path (R7 + rotation/unroll) =================
        const int j0 = (by - 8) * 12;
        float (*sbuf)[HH] = (float(*)[HH])smem;     // [12][256]
        float* outc = out + NN*NN;

        for (int idx = t; idx < 12*HH/4; idx += 256) {
            const int jj = idx >> 6;            // 64 float4s per row
            const int h4 = (idx & 63) << 2;
            const float4 a = *(const float4*)&ta[i*HH + h4];
            const float4 b = *(const float4*)&tb[(j0 + jj)*HH + h4];
            float4 s; s.x = a.x + b.x; s.y = a.y + b.y; s.z = a.z + b.z; s.w = a.w + b.w;
            *(float4*)&sbuf[jj][h4] = s;
        }
        __syncthreads();

        if (t < 192) {
            const int g  = t / 48;              // j-group 0..3
            const int l  = t % 48;              // k-pair lane
            const int k0 = 2*l;
            const int c0 = (t >> 6) * 21;       // rotated start chunk (wave 0/1/2)

            v2f acc[3][2];
            #pragma unroll
            for (int m = 0; m < 3; ++m) { acc[m][0] = (v2f)(0.f); acc[m][1] = (v2f)(0.f); }

            const float* __restrict__ sb0 = &sbuf[g*3 + 0][0];
            const float* __restrict__ sb1 = &sbuf[g*3 + 1][0];
            const float* __restrict__ sb2 = &sbuf[g*3 + 2][0];

#define CONF_CHUNK(H0)                                                        \
            {                                                                 \
                const int h0 = (H0);                                          \
                const float4 tA = *(const float4*)&tcP[((h0 >> 1)    *NN + k0)*2]; \
                const float4 tB = *(const float4*)&tcP[(((h0 >> 1)+1)*NN + k0)*2]; \
                const float4 vv = *(const float4*)&V2[h0];                    \
                const float4 sA = *(const float4*)&sb0[h0];                   \
                const float4 sB = *(const float4*)&sb1[h0];                   \
                const float4 sC = *(const float4*)&sb2[h0];                   \
                const v2f va01 = {vv.x, vv.y}, va23 = {vv.z, vv.w};           \
                const v2f tk0a = {tA.x, tA.y}, tk1a = {tA.z, tA.w};           \
                const v2f tk0b = {tB.x, tB.y}, tk1b = {tB.z, tB.w};           \
                const v2f sp[3][2] = {{{sA.x,sA.y},{sA.z,sA.w}},              \
                                      {{sB.x,sB.y},{sB.z,sB.w}},              \
                                      {{sC.x,sC.y},{sC.z,sC.w}}};             \
                _Pragma("unroll")                                             \
                for (int m = 0; m < 3; ++m) {                                 \
                    v2f x;                                                    \
                    x = sp[m][0] + tk0a;                                      \
                    x.x = fmaxf(x.x, 0.f); x.y = fmaxf(x.y, 0.f);             \
                    acc[m][0] += x * va01;                                    \
                    x = sp[m][0] + tk1a;                                      \
                    x.x = fmaxf(x.x, 0.f); x.y = fmaxf(x.y, 0.f);             \
                    acc[m][1] += x * va01;                                    \
                    x = sp[m][1] + tk0b;                                      \
                    x.x = fmaxf(x.x, 0.f); x.y = fmaxf(x.y, 0.f);             \
                    acc[m][0] += x * va23;                                    \
                    x = sp[m][1] + tk1b;                                      \
                    x.x = fmaxf(x.x, 0.f); x.y = fmaxf(x.y, 0.f);             \
                    acc[m][1] += x * va23;                                    \
                }                                                             \
            }

            #pragma unroll 8
            for (int c = c0; c < 64; ++c) CONF_CHUNK(c << 2)
            #pragma unroll 8
            for (int c = 0; c < c0; ++c) CONF_CHUNK(c << 2)
#undef CONF_CHUNK

            const float c2v = c2[0];
            #pragma unroll
            for (int m = 0; m < 3; ++m) {
                const int j = j0 + g*3 + m;
                const float a0 = acc[m][0].x + acc[m][0].y;
                const float a1 = acc[m][1].x + acc[m][1].y;
                float2 o;
                o.x = 1.f / (1.f + __expf(-(a0 + c2v)));
                o.y = 1.f / (1.f + __expf(-(a1 + c2v)));
                if (i == j || i == k0   || j == k0  ) o.x = 0.f;
                if (i == j || i == k0+1 || j == k0+1) o.y = 0.f;
                *(float2*)&outc[(i*NN + j)*NN + k0] = o;
            }
        }
    }
}

extern "C" void kernel_launch(void* const* d_in, const int* in_sizes, int n_in,
                              void* d_out, int out_size, void* d_ws, size_t ws_size,
                              hipStream_t stream) {
    const float* X  = (const float*)d_in[0];
    // d_in[1] = edge_index (unused by reference)
    const float* W1 = (const float*)d_in[2];
    const float* b1 = (const float*)d_in[3];
    const float* W2 = (const float*)d_in[4];
    const float* b2 = (const float*)d_in[5];
    const float* W3 = (const float*)d_in[6];
    const float* b3 = (const float*)d_in[7];
    const float* V1 = (const float*)d_in[8];
    const float* c1 = (const float*)d_in[9];
    const float* V2 = (const float*)d_in[10];
    const float* c2 = (const float*)d_in[11];

    float* out = (float*)d_out;
    float* ws  = (float*)d_ws;
    float* pi  = ws;                 // 96*256
    float* pj  = pi + NN*HH;
    float* ta  = pj + NN*HH;
    float* tb  = ta + NN*HH;
    float* tcP = tb + NN*HH;         // 128*96 float2 = 256*96 floats

    proj_kernel<<<NN, 256, 0, stream>>>(X, W1, b1, V1, c1, pi, pj, ta, tb, tcP);
    fused_kernel<<<dim3(NN, 16), 256, 0, stream>>>(pi, pj, W2, b2, W3, b3,
                                                   ta, tb, tcP, V2, c2, out);
}

// Round 11
// 40.965 us; speedup vs baseline: 1.2500x; 1.1041x over previous
//
#include <hip/hip_runtime.h>
#include <hip/hip_bf16.h>

#define NN 96
#define DD 64
#define HH 256
#define H2 128

typedef float v2f __attribute__((ext_vector_type(2)));

// ---------------- Kernel A: projections ----------------
// tc written h-paired: tcP[(hp*NN + k)*2 + (h&1)] so conf loads float2
// h-pairs (float4 = k-pair of h-pairs) for packed math.
__global__ __launch_bounds__(256) void proj_kernel(
    const float* __restrict__ X, const float* __restrict__ W1, const float* __restrict__ b1,
    const float* __restrict__ V1, const float* __restrict__ c1,
    float* __restrict__ pi, float* __restrict__ pj,
    float* __restrict__ ta, float* __restrict__ tb, float* __restrict__ tcP)
{
    const int i = blockIdx.x;
    const int h = threadIdx.x;          // 0..255
    __shared__ float xs[DD];
    if (h < DD) xs[h] = X[i*DD + h];
    __syncthreads();
    float aPi = 0.f, aPj = 0.f, aTa = 0.f, aTb = 0.f, aTc = 0.f;
    #pragma unroll 8
    for (int d = 0; d < DD; ++d) {
        const float x = xs[d];
        aPi = fmaf(x, W1[d*HH + h],          aPi);
        aPj = fmaf(x, W1[(DD + d)*HH + h],   aPj);
        aTa = fmaf(x, V1[d*HH + h],          aTa);
        aTb = fmaf(x, V1[(DD + d)*HH + h],   aTb);
        aTc = fmaf(x, V1[(2*DD + d)*HH + h], aTc);
    }
    pi[i*HH + h] = aPi + b1[h];
    pj[i*HH + h] = aPj;
    ta[i*HH + h] = aTa + c1[h];
    tb[i*HH + h] = aTb;
    tcP[((h >> 1)*NN + i)*2 + (h & 1)] = aTc;
}

// ---------------- Fused kernel: causal (by<8) + conf (by>=8) ----------------
// R8-proven structure (packed f32, grid (96,16), 6 blocks/CU, in-order
// h-loop = L1/L2 broadcast reuse across waves). This round's single change:
// conf relu uses __builtin_elementwise_max -> v_pk_max_f32, cutting the
// conf inner from 4 to 3 VOP3P inst per h-pair (-25% VALU on the dominant
// path). Numerics bit-identical.
__global__ __launch_bounds__(256) void fused_kernel(
    const float* __restrict__ pi, const float* __restrict__ pj,
    const float* __restrict__ W2, const float* __restrict__ b2,
    const float* __restrict__ W3, const float* __restrict__ b3,
    const float* __restrict__ ta, const float* __restrict__ tb,
    const float* __restrict__ tcP, const float* __restrict__ V2,
    const float* __restrict__ c2, float* __restrict__ out)
{
    __shared__ float smem[4*64*2*12 + 2*12];   // causal(6144+24) / conf(3072)
    const int i  = blockIdx.x;
    const int by = blockIdx.y;
    const int t  = threadIdx.x;         // 0..255

    if (by < 8) {
        // ================= causal path (R7/R8-exact) =================
        const int j0 = by * 12;
        const int c2c = t & 63;
        const int qt  = t >> 6;         // 0..3

        float (*hb)[12]          = (float(*)[12])smem;          // [256][12]
        float (*part)[64][2][12] = (float(*)[64][2][12])smem;   // [4][64][2][12]
        float (*red)[12]         = (float(*)[12])(smem + 6144); // [2][12]

        {
            const float p_i = pi[i*HH + t];
            #pragma unroll
            for (int jj = 0; jj < 12; ++jj)
                hb[t][jj] = fmaxf(p_i + pj[(j0 + jj)*HH + t], 0.f);
        }
        __syncthreads();

        v2f acc0[6], acc1[6];
        #pragma unroll
        for (int p = 0; p < 6; ++p) { acc0[p] = (v2f)(0.f); acc1[p] = (v2f)(0.f); }

        const float* __restrict__ w2p = W2 + (qt*64)*H2 + c2c;
        #pragma unroll 2
        for (int q = 0; q < 64; ++q) {
            const float wa = w2p[q*H2];
            const float wb = w2p[q*H2 + 64];
            const v2f wa2 = {wa, wa};
            const v2f wb2 = {wb, wb};
            const int hq = qt*64 + q;
            const float4 hA = *(const float4*)&hb[hq][0];
            const float4 hB = *(const float4*)&hb[hq][4];
            const float4 hC = *(const float4*)&hb[hq][8];
            const v2f hp[6] = {{hA.x,hA.y},{hA.z,hA.w},
                               {hB.x,hB.y},{hB.z,hB.w},
                               {hC.x,hC.y},{hC.z,hC.w}};
            #pragma unroll
            for (int p = 0; p < 6; ++p) {
                acc0[p] += hp[p] * wa2;     // v_pk_fma_f32
                acc1[p] += hp[p] * wb2;
            }
        }
        __syncthreads();          // all hb reads done before overwrite

        #pragma unroll
        for (int b = 0; b < 3; ++b) {
            float4 p0, p1;
            p0.x = acc0[b*2].x; p0.y = acc0[b*2].y; p0.z = acc0[b*2+1].x; p0.w = acc0[b*2+1].y;
            p1.x = acc1[b*2].x; p1.y = acc1[b*2].y; p1.z = acc1[b*2+1].x; p1.w = acc1[b*2+1].y;
            *(float4*)&part[qt][c2c][0][b*4] = p0;
            *(float4*)&part[qt][c2c][1][b*4] = p1;
        }
        __syncthreads();

        if (t < 128) {
            const int cl = t & 63;
            const int cc = t >> 6;
            const float b2c = b2[t];
            const float w3c = W3[t];
            float v[12];
            #pragma unroll
            for (int b = 0; b < 3; ++b) {
                float4 s; s.x = 0.f; s.y = 0.f; s.z = 0.f; s.w = 0.f;
                #pragma unroll
                for (int qq = 0; qq < 4; ++qq) {
                    const float4 p = *(const float4*)&part[qq][cl][cc][b*4];
                    s.x += p.x; s.y += p.y; s.z += p.z; s.w += p.w;
                }
                v[b*4+0] = fmaxf(s.x + b2c, 0.f) * w3c;
                v[b*4+1] = fmaxf(s.y + b2c, 0.f) * w3c;
                v[b*4+2] = fmaxf(s.z + b2c, 0.f) * w3c;
                v[b*4+3] = fmaxf(s.w + b2c, 0.f) * w3c;
            }
            #pragma unroll
            for (int jj = 0; jj < 12; ++jj) {
                float s = v[jj];
                #pragma unroll
                for (int off = 32; off; off >>= 1) s += __shfl_down(s, off, 64);
                if ((t & 63) == 0) red[t >> 6][jj] = s;
            }
        }
        __syncthreads();
        if (t < 12) {
            const int j = j0 + t;
            const float s = red[0][t] + red[1][t] + b3[0];
            out[i*NN + j] = (i == j) ? 0.f : 1.f / (1.f + __expf(-s));
        }
    } else {
        // ================= conf path (R8 + v_pk_max_f32 relu) =================
        const int j0 = (by - 8) * 12;
        float (*sbuf)[HH] = (float(*)[HH])smem;     // [12][256]
        float* outc = out + NN*NN;

        for (int idx = t; idx < 12*HH/4; idx += 256) {
            const int jj = idx >> 6;            // 64 float4s per row
            const int h4 = (idx & 63) << 2;
            const float4 a = *(const float4*)&ta[i*HH + h4];
            const float4 b = *(const float4*)&tb[(j0 + jj)*HH + h4];
            float4 s; s.x = a.x + b.x; s.y = a.y + b.y; s.z = a.z + b.z; s.w = a.w + b.w;
            *(float4*)&sbuf[jj][h4] = s;
        }
        __syncthreads();

        if (t < 192) {
            const int g  = t / 48;              // j-group 0..3
            const int l  = t % 48;              // k-pair lane
            const int k0 = 2*l;

            v2f acc[3][2];                      // [m][kk], packed over h-pair
            #pragma unroll
            for (int m = 0; m < 3; ++m) { acc[m][0] = (v2f)(0.f); acc[m][1] = (v2f)(0.f); }

            const float* __restrict__ sb0 = &sbuf[g*3 + 0][0];
            const float* __restrict__ sb1 = &sbuf[g*3 + 1][0];
            const float* __restrict__ sb2 = &sbuf[g*3 + 2][0];
            const v2f vzero = (v2f)(0.f);

            #pragma unroll 2
            for (int h0 = 0; h0 < HH; h0 += 4) {
                // tA = {tc[h0][k0], tc[h0+1][k0], tc[h0][k0+1], tc[h0+1][k0+1]}
                const float4 tA = *(const float4*)&tcP[((h0 >> 1)    *NN + k0)*2];
                const float4 tB = *(const float4*)&tcP[(((h0 >> 1)+1)*NN + k0)*2];
                const float4 vv = *(const float4*)&V2[h0];        // uniform
                const float4 sA = *(const float4*)&sb0[h0];
                const float4 sB = *(const float4*)&sb1[h0];
                const float4 sC = *(const float4*)&sb2[h0];
                const v2f va01 = {vv.x, vv.y}, va23 = {vv.z, vv.w};
                const v2f tk0a = {tA.x, tA.y}, tk1a = {tA.z, tA.w};
                const v2f tk0b = {tB.x, tB.y}, tk1b = {tB.z, tB.w};
                const v2f sp[3][2] = {{{sA.x,sA.y},{sA.z,sA.w}},
                                      {{sB.x,sB.y},{sB.z,sB.w}},
                                      {{sC.x,sC.y},{sC.z,sC.w}}};
                #pragma unroll
                for (int m = 0; m < 3; ++m) {
                    v2f x;
                    x = __builtin_elementwise_max(sp[m][0] + tk0a, vzero); // pk_add+pk_max
                    acc[m][0] += x * va01;                                 // pk_fma
                    x = __builtin_elementwise_max(sp[m][0] + tk1a, vzero);
                    acc[m][1] += x * va01;
                    x = __builtin_elementwise_max(sp[m][1] + tk0b, vzero);
                    acc[m][0] += x * va23;
                    x = __builtin_elementwise_max(sp[m][1] + tk1b, vzero);
                    acc[m][1] += x * va23;
                }
            }

            const float c2v = c2[0];
            #pragma unroll
            for (int m = 0; m < 3; ++m) {
                const int j = j0 + g*3 + m;
                const float a0 = acc[m][0].x + acc[m][0].y;
                const float a1 = acc[m][1].x + acc[m][1].y;
                float2 o;
                o.x = 1.f / (1.f + __expf(-(a0 + c2v)));
                o.y = 1.f / (1.f + __expf(-(a1 + c2v)));
                if (i == j || i == k0   || j == k0  ) o.x = 0.f;
                if (i == j || i == k0+1 || j == k0+1) o.y = 0.f;
                *(float2*)&outc[(i*NN + j)*NN + k0] = o;
            }
        }
    }
}

extern "C" void kernel_launch(void* const* d_in, const int* in_sizes, int n_in,
                              void* d_out, int out_size, void* d_ws, size_t ws_size,
                              hipStream_t stream) {
    const float* X  = (const float*)d_in[0];
    // d_in[1] = edge_index (unused by reference)
    const float* W1 = (const float*)d_in[2];
    const float* b1 = (const float*)d_in[3];
    const float* W2 = (const float*)d_in[4];
    const float* b2 = (const float*)d_in[5];
    const float* W3 = (const float*)d_in[6];
    const float* b3 = (const float*)d_in[7];
    const float* V1 = (const float*)d_in[8];
    const float* c1 = (const float*)d_in[9];
    const float* V2 = (const float*)d_in[10];
    const float* c2 = (const float*)d_in[11];

    float* out = (float*)d_out;
    float* ws  = (float*)d_ws;
    float* pi  = ws;                 // 96*256
    float* pj  = pi + NN*HH;
    float* ta  = pj + NN*HH;
    float* tb  = ta + NN*HH;
    float* tcP = tb + NN*HH;         // 128*96 float2 = 256*96 floats

    proj_kernel<<<NN, 256, 0, stream>>>(X, W1, b1, V1, c1, pi, pj, ta, tb, tcP);
    fused_kernel<<<dim3(NN, 16), 256, 0, stream>>>(pi, pj, W2, b2, W3, b3,
                                                   ta, tb, tcP, V2, c2, out);
}